// Round 2
// baseline (189.899 us; speedup 1.0000x reference)
//
#include <hip/hip_runtime.h>

typedef _Float16 f16;
typedef _Float16 f16x8 __attribute__((ext_vector_type(8)));
typedef __fp16   fp16x2 __attribute__((ext_vector_type(2)));
typedef float    f32x16 __attribute__((ext_vector_type(16)));
typedef float    f32x4  __attribute__((ext_vector_type(4)));
typedef unsigned int u32;
typedef unsigned int u32x4 __attribute__((ext_vector_type(4)));

#define NPTS 262144

// ---- packed layout in d_ws ----
// f16 weights, per net (net0=diffuse, net1=specular), net stride 143360 f16:
//   L0:   [0      .. 4096)   frag[mt][lane][8]   (K padded to 16; k>=K0 zeroed)
//   L1:   [4096   .. 69632)  frag[kt][mt][lane][8]
//   L2:   [69632  .. 135168) frag[kt][mt][lane][8]
//   L3:   [135168 .. 143360) frag[kt][lane][8]   (m = lane&31, only m<3 valid)
// A-frag convention (mfma_f32_32x32x16_f16): A[m][k], m = 32*mt + (lane&31),
//   k = 16*kt + 8*(lane>>5) + j. A[m][k] = W[k][m] (reference does x @ W).
// f32 biases at byte 573440, 800 floats per net:
//   B0[256] B1[256] B2[256] B3[32], each packed as [mt][hi][reg] matching the
//   C/D layout row = (reg&3) + 8*(reg>>2) + 4*hi  (so acc can be bias-initialized).
#define NET_F16   143360
#define L1_OFF    4096
#define L2_OFF    69632
#define L3_OFF    135168
#define BIAS_BYTE 573440

static __device__ __forceinline__ u32 pkrtz(float a, float b) {
    fp16x2 h = __builtin_amdgcn_cvt_pkrtz(a, b);
    return __builtin_bit_cast(u32, h);
}

// ---------------- weight/bias packing kernel (runs every launch; ~1.7MB) ----------------
__global__ void prep_kernel(
    const float* __restrict__ dW0, const float* __restrict__ db0,
    const float* __restrict__ dW1, const float* __restrict__ db1,
    const float* __restrict__ dW2, const float* __restrict__ db2,
    const float* __restrict__ dW3, const float* __restrict__ db3,
    const float* __restrict__ sW0, const float* __restrict__ sb0,
    const float* __restrict__ sW1, const float* __restrict__ sb1,
    const float* __restrict__ sW2, const float* __restrict__ sb2,
    const float* __restrict__ sW3, const float* __restrict__ sb3,
    f16* __restrict__ wpk, float* __restrict__ bpk)
{
    const int ROWS = 17920;           // 8-f16 fragment rows per net
    int t = blockIdx.x * 256 + threadIdx.x;
    if (t < 2 * ROWS) {
        int net = (t >= ROWS) ? 1 : 0;
        int r = t - net * ROWS;
        const float* W0 = net ? sW0 : dW0;
        const float* W1 = net ? sW1 : dW1;
        const float* W2 = net ? sW2 : dW2;
        const float* W3 = net ? sW3 : dW3;
        int K0 = net ? 8 : 3;
        f16* o = wpk + net * NET_F16;
        if (r < 512) {                                   // L0: frag[mt][lane]
            int lane = r & 63;
            int m  = 32 * (r >> 6) + (lane & 31);
            int kb = 8 * (lane >> 5);
            f16* q = o + r * 8;
            #pragma unroll
            for (int j = 0; j < 8; ++j) {
                int k = kb + j;
                q[j] = (f16)((k < K0) ? W0[k * 256 + m] : 0.0f);
            }
        } else if (r < 512 + 8192) {                     // L1: frag[kt][mt][lane]
            int rr = r - 512;
            int lane = rr & 63;
            int m  = 32 * ((rr >> 6) & 7) + (lane & 31);
            int kb = 16 * (rr >> 9) + 8 * (lane >> 5);
            f16* q = o + L1_OFF + rr * 8;
            #pragma unroll
            for (int j = 0; j < 8; ++j) q[j] = (f16)W1[(kb + j) * 256 + m];
        } else if (r < 512 + 16384) {                    // L2
            int rr = r - (512 + 8192);
            int lane = rr & 63;
            int m  = 32 * ((rr >> 6) & 7) + (lane & 31);
            int kb = 16 * (rr >> 9) + 8 * (lane >> 5);
            f16* q = o + L2_OFF + rr * 8;
            #pragma unroll
            for (int j = 0; j < 8; ++j) q[j] = (f16)W2[(kb + j) * 256 + m];
        } else {                                         // L3: frag[kt][lane]
            int rr = r - (512 + 16384);
            int lane = rr & 63;
            int m  = lane & 31;
            int kb = 16 * (rr >> 6) + 8 * (lane >> 5);
            f16* q = o + L3_OFF + rr * 8;
            #pragma unroll
            for (int j = 0; j < 8; ++j)
                q[j] = (f16)((m < 3) ? W3[(kb + j) * 3 + m] : 0.0f);
        }
    } else if (t < 2 * ROWS + 1600) {                    // biases
        int tb = t - 2 * ROWS;
        int net = (tb >= 800) ? 1 : 0;
        int i = tb - net * 800;
        float val;
        if (i < 768) {
            int layer = i >> 8;
            const float* bl = net ? (layer == 0 ? sb0 : layer == 1 ? sb1 : sb2)
                                  : (layer == 0 ? db0 : layer == 1 ? db1 : db2);
            int q  = i & 255;
            int rg = q & 15, h = (q >> 4) & 1;
            int m  = 32 * (q >> 5) + (rg & 3) + 8 * (rg >> 2) + 4 * h;
            val = bl[m];
        } else {
            int q  = i - 768;
            int rg = q & 15, h = q >> 4;
            int m  = (rg & 3) + 8 * (rg >> 2) + 4 * h;
            const float* b3 = net ? sb3 : db3;
            val = (m < 3) ? b3[m] : 0.0f;
        }
        bpk[net * 800 + i] = val;
    }
}

// ---------------- fused dual-MLP kernel ----------------
// 256 thr = 4 waves/block, 32 points/wave, 128 points/block, grid 2048.
// Activations live in registers as B-fragments of X^T (point = lane&31).
__launch_bounds__(256, 2)
__global__ void mlp_kernel(const float* __restrict__ gn, const float* __restrict__ gv,
                           const float* __restrict__ gro, const float* __restrict__ gr0,
                           const f16* __restrict__ wpk, const float* __restrict__ bpk,
                           float* __restrict__ out)
{
    __shared__ u32x4 ldsq[2][512];   // double-buffered 8KB weight K-chunks

    const int tid  = threadIdx.x;
    const int wave = tid >> 6;
    const int lane = tid & 63;
    const int l32  = lane & 31;
    const int hi   = lane >> 5;
    const int p    = blockIdx.x * 128 + wave * 32 + l32;

    // ---- inputs: normalize, visibility, build layer-0 B-fragments ----
    u32x4 xin0 = {0, 0, 0, 0};   // diffuse input frag (k0..2 = n; rest 0)
    u32x4 xin1 = {0, 0, 0, 0};   // specular input frag (k0..7 = n,v,rough,r0)
    bool vis = false;
    if (hi == 0) {               // hi lanes hold k=8..15 which are all zero-padded
        float nx = gn[3 * p + 0], ny = gn[3 * p + 1], nz = gn[3 * p + 2];
        float vx = gv[3 * p + 0], vy = gv[3 * p + 1], vz = gv[3 * p + 2];
        float ro = gro[p], rr = gr0[p];
        float ni = 1.0f / fmaxf(sqrtf(nx * nx + ny * ny + nz * nz), 1e-12f);
        float vi = 1.0f / fmaxf(sqrtf(vx * vx + vy * vy + vz * vz), 1e-12f);
        nx *= ni; ny *= ni; nz *= ni;
        vx *= vi; vy *= vi; vz *= vi;
        vis = (nx * vx + ny * vy + nz * vz) > 0.0f;
        xin0[0] = pkrtz(nx, ny); xin0[1] = pkrtz(nz, 0.0f);
        xin1[0] = xin0[0];       xin1[1] = pkrtz(nz, vx);
        xin1[2] = pkrtz(vy, vz); xin1[3] = pkrtz(ro, rr);
    }

    u32x4  xf[16];    // X^T B-fragments for current layer (K=256) - 64 VGPRs
    f32x16 acc[8];    // Y^T accumulators, 8 M-tiles of 32   - 128 VGPRs

    #pragma unroll 1
    for (int net = 0; net < 2; ++net) {
        const f16*   wp = wpk + net * NET_F16;
        const float* bp = bpk + net * 800;
        u32x4 xin = xin0;
        if (net) xin = xin1;
        const f16x8 xinh = __builtin_bit_cast(f16x8, xin);

        // epilogue: acc (Y^T, C/D layout) -> ReLU -> f16 -> next-layer B-frags.
        // C/D row = (r&3)+8*(r>>2)+4*hi ; B-frag k = 8*hi+j. The half-lane
        // exchange is shfl_xor(32) + select (permlane32_swap decomposition).
        auto epilogue = [&]() {
            #pragma unroll
            for (int mt = 0; mt < 8; ++mt) {
                f32x16 c = acc[mt];
                #pragma unroll
                for (int g = 0; g < 16; ++g) c[g] = fmaxf(c[g], 0.0f);
                #pragma unroll
                for (int q = 0; q < 2; ++q) {
                    u32 a0 = pkrtz(c[8 * q + 0], c[8 * q + 1]);  // regs 4*(2q)+0..3
                    u32 a1 = pkrtz(c[8 * q + 2], c[8 * q + 3]);
                    u32 b0 = pkrtz(c[8 * q + 4], c[8 * q + 5]);  // regs 4*(2q+1)+0..3
                    u32 b1 = pkrtz(c[8 * q + 6], c[8 * q + 7]);
                    u32 xa0 = (u32)__shfl_xor((int)a0, 32);
                    u32 xa1 = (u32)__shfl_xor((int)a1, 32);
                    u32 xb0 = (u32)__shfl_xor((int)b0, 32);
                    u32 xb1 = (u32)__shfl_xor((int)b1, 32);
                    u32x4 w;
                    w[0] = hi ? xb0 : a0;   // j0,j1  (from lo partner)
                    w[1] = hi ? xb1 : a1;   // j2,j3
                    w[2] = hi ? b0  : xa0;  // j4,j5  (from hi partner)
                    w[3] = hi ? b1  : xa1;  // j6,j7
                    xf[2 * mt + q] = w;
                }
            }
        };

        // 256x256 layer: bias-init acc, 16 K-steps, LDS-staged W fragments.
        auto layer256 = [&](const f16* wl, const float* bl) {
            const u32x4* wq = (const u32x4*)wl;
            #pragma unroll
            for (int mt = 0; mt < 8; ++mt) {
                const f32x4* b4 = (const f32x4*)(bl + mt * 32 + hi * 16);
                f32x4 v0 = b4[0], v1 = b4[1], v2 = b4[2], v3 = b4[3];
                #pragma unroll
                for (int j = 0; j < 4; ++j) {
                    acc[mt][j] = v0[j]; acc[mt][4 + j] = v1[j];
                    acc[mt][8 + j] = v2[j]; acc[mt][12 + j] = v3[j];
                }
            }
            // prologue: stage kt=0 chunk (wave w stages mt slices w and w+4)
            ldsq[0][wave * 64 + lane]       = wq[wave * 64 + lane];
            ldsq[0][(wave + 4) * 64 + lane] = wq[(wave + 4) * 64 + lane];
            #pragma unroll
            for (int kt = 0; kt < 16; ++kt) {
                __syncthreads();                       // publish buf[kt&1]
                u32x4 nxt0 = {0,0,0,0}, nxt1 = {0,0,0,0};
                if (kt < 15) {                         // issue next-chunk loads early
                    nxt0 = wq[(kt + 1) * 512 + wave * 64 + lane];
                    nxt1 = wq[(kt + 1) * 512 + (wave + 4) * 64 + lane];
                }
                const u32x4* bufq = &ldsq[kt & 1][0];
                const f16x8 xh = __builtin_bit_cast(f16x8, xf[kt]);
                #pragma unroll
                for (int mt = 0; mt < 8; ++mt) {
                    f16x8 a = __builtin_bit_cast(f16x8, bufq[mt * 64 + lane]);
                    acc[mt] = __builtin_amdgcn_mfma_f32_32x32x16_f16(a, xh, acc[mt], 0, 0, 0);
                }
                if (kt < 15) {                         // write-late into other buffer
                    ldsq[(kt + 1) & 1][wave * 64 + lane]       = nxt0;
                    ldsq[(kt + 1) & 1][(wave + 4) * 64 + lane] = nxt1;
                }
            }
        };

        // ---------- L0 (K padded to 16, fragments straight from L2) ----------
        {
            const u32x4* w0q = (const u32x4*)wp;
            #pragma unroll
            for (int mt = 0; mt < 8; ++mt) {
                const f32x4* b4 = (const f32x4*)(bp + mt * 32 + hi * 16);
                f32x4 v0 = b4[0], v1 = b4[1], v2 = b4[2], v3 = b4[3];
                f32x16 c;
                #pragma unroll
                for (int j = 0; j < 4; ++j) {
                    c[j] = v0[j]; c[4 + j] = v1[j]; c[8 + j] = v2[j]; c[12 + j] = v3[j];
                }
                f16x8 a = __builtin_bit_cast(f16x8, w0q[mt * 64 + lane]);
                acc[mt] = __builtin_amdgcn_mfma_f32_32x32x16_f16(a, xinh, c, 0, 0, 0);
            }
        }
        epilogue();

        layer256(wp + L1_OFF, bp + 256);
        epilogue();
        layer256(wp + L2_OFF, bp + 512);
        epilogue();

        // ---------- L3: 256 -> 3 (one padded M-tile, fragments from L2) ----------
        {
            const f32x4* b4 = (const f32x4*)(bp + 768 + hi * 16);
            f32x4 v0 = b4[0], v1 = b4[1], v2 = b4[2], v3 = b4[3];
            f32x16 c;
            #pragma unroll
            for (int j = 0; j < 4; ++j) {
                c[j] = v0[j]; c[4 + j] = v1[j]; c[8 + j] = v2[j]; c[12 + j] = v3[j];
            }
            const u32x4* w3q = (const u32x4*)(wp + L3_OFF);
            #pragma unroll
            for (int kt = 0; kt < 16; ++kt) {
                f16x8 a = __builtin_bit_cast(f16x8, w3q[kt * 64 + lane]);
                c = __builtin_amdgcn_mfma_f32_32x32x16_f16(
                        a, __builtin_bit_cast(f16x8, xf[kt]), c, 0, 0, 0);
            }
            // C/D rows 0..2 at hi=0 are the 3 outputs for point p (lane&31)
            if (hi == 0) {
                float* op = out + net * (NPTS * 3) + p * 3;
                op[0] = vis ? c[0] : 0.0f;
                op[1] = vis ? c[1] : 0.0f;
                op[2] = vis ? c[2] : 0.0f;
            }
        }
    }
}

extern "C" void kernel_launch(void* const* d_in, const int* in_sizes, int n_in,
                              void* d_out, int out_size, void* d_ws, size_t ws_size,
                              hipStream_t stream)
{
    // d_in: 0 normals, 1 view_dirs, 2 roughness, 3 r0,
    //       4..11 dW0,db0,dW1,db1,dW2,db2,dW3,db3, 12..19 sW0..sb3
    f16*   wpk = (f16*)d_ws;                       // 573440 B of packed f16 weights
    float* bpk = (float*)((char*)d_ws + BIAS_BYTE); // 6400 B of packed biases

    prep_kernel<<<147, 256, 0, stream>>>(
        (const float*)d_in[4],  (const float*)d_in[5],
        (const float*)d_in[6],  (const float*)d_in[7],
        (const float*)d_in[8],  (const float*)d_in[9],
        (const float*)d_in[10], (const float*)d_in[11],
        (const float*)d_in[12], (const float*)d_in[13],
        (const float*)d_in[14], (const float*)d_in[15],
        (const float*)d_in[16], (const float*)d_in[17],
        (const float*)d_in[18], (const float*)d_in[19],
        wpk, bpk);

    mlp_kernel<<<2048, 256, 0, stream>>>(
        (const float*)d_in[0], (const float*)d_in[1],
        (const float*)d_in[2], (const float*)d_in[3],
        wpk, bpk, (float*)d_out);
}